// Round 1
// 144.763 us; speedup vs baseline: 1.0128x; 1.0128x over previous
//
#include <hip/hip_runtime.h>

// ---------------------------------------------------------------------------
// Compile-time Cayley tables for PGA G(3,0,1), basis ordered by grade:
// idx: 0:1 1:e0 2:e1 3:e2 4:e3 5:e01 6:e02 7:e03 8:e12 9:e13 10:e23
//      11:e012 12:e013 13:e023 14:e123 15:e0123
// Blade as 4-bit mask: e0=bit0, e1=bit1, e2=bit2, e3=bit3.
// ---------------------------------------------------------------------------
namespace ga {

constexpr int MASK[16]        = {0,1,2,4,8,3,5,9,6,10,12,7,11,13,14,15};
constexpr int IDX_OF_MASK[16] = {0,1,2,5,3,6,8,11,4,7,9,12,10,13,14,15};

constexpr int popc(int v) { int c = 0; while (v) { c += v & 1; v >>= 1; } return c; }

constexpr int reorder_sign(int a, int b) {
    int s = 0; int t = a >> 1;
    while (t) { s += popc(t & b); t >>= 1; }
    return (s & 1) ? -1 : 1;
}

struct Term { signed char i, j, k, s; };

// Geometric product, metric (0,1,1,1): 192 nonzero terms.
struct GPTab { Term t[192]; };
constexpr GPTab build_gp() {
    GPTab T{}; int n = 0;
    for (int i = 0; i < 16; i++)
        for (int j = 0; j < 16; j++) {
            int a = MASK[i], b = MASK[j];
            if (a & b & 1) continue;                 // e0^2 = 0
            T.t[n].i = (signed char)i;
            T.t[n].j = (signed char)j;
            T.t[n].k = (signed char)IDX_OF_MASK[a ^ b];
            T.t[n].s = (signed char)reorder_sign(a, b);
            n++;
        }
    return T;
}

// Join (sans ref scale): dual(dual(x) ^ dual(y)) folded to 81 terms.
struct JNTab { Term t[81]; };
constexpr JNTab build_join() {
    JNTab T{}; int n = 0;
    int didx[16] = {}, dsgn[16] = {};
    for (int i = 0; i < 16; i++) {
        int a = MASK[i], c = (~a) & 0xF;
        didx[i] = IDX_OF_MASK[c];
        dsgn[i] = reorder_sign(a, c);
    }
    for (int i = 0; i < 16; i++)
        for (int j = 0; j < 16; j++) {
            int p = didx[i], q = didx[j];
            int a = MASK[p], b = MASK[q];
            if (a & b) continue;
            int m = IDX_OF_MASK[a | b];
            int k = didx[m];
            int s = dsgn[i] * dsgn[j] * dsgn[m] * reorder_sign(a, b);
            T.t[n].i = (signed char)i;
            T.t[n].j = (signed char)j;
            T.t[n].k = (signed char)k;
            T.t[n].s = (signed char)s;
            n++;
        }
    return T;
}

constexpr GPTab G = build_gp();
constexpr JNTab J = build_join();

} // namespace ga

// ---------------------------------------------------------------------------
// R8: occupancy over software pipelining.
//
// R7 post-mortem: warm dispatches (inputs L3-resident) ran at the same
// ~49 us as cold -> NOT DRAM-BW-bound. VALUBusy 11%, conflicts ~220 cy/chunk
// -> not VALU/LDS-bound. The cap was LDS: 18.9 KB (double buffer) -> 8
// single-wave blocks/CU = 2 waves/SIMD (OccupancyPercent 15%); the 1-deep
// prefetch couldn't cover exposed memory latency at that TLP.
//
// R8 change: one 64-point chunk per block, grid = nchunks (8192). Single
// buffer -> LDS drops to 9 472 B -> 16 blocks/CU; VGPR becomes the wave cap,
// enforced <=128 via __launch_bounds__(64, 4) -> 4 waves/SIMD, 2x occupancy.
// Chunk DMA latency is hidden by 16 independent resident waves (TLP) instead
// of an in-wave prefetch.
//
// Kept from R7 (all validated there):
//   * 9 global_load_lds DMAs per chunk (zero staging VGPRs; wave-uniform
//     base + lane*16 -> unpadded point-major layout, 4-way frag conflict
//     accepted).
//   * 36-stride LDS overlay over the same buffer for the output transpose
//     (conflict-free), then unit-stride cooperative float4 stores (1 KB
//     contiguous per instruction = full 128B lines).
//   * No __syncthreads (single-wave block, wave-private LDS), asm memory
//     fences for the cross-lane WAR (R3 lesson).
// ---------------------------------------------------------------------------
constexpr int BUF_FLOATS = 2304;   // x[0..1024) | y[1024..2048); overlay spans [0..2304)
constexpr int OSTRIDE    = 36;

typedef const __attribute__((address_space(1))) void* gas_ptr;
typedef __attribute__((address_space(3))) void*       las_ptr;

__global__ __launch_bounds__(64, 4)
void MVGeometricBilinear_kernel(const float* __restrict__ x,
                                const float* __restrict__ y,
                                const float* __restrict__ ref,
                                float* __restrict__ out,
                                int nchunks)
{
    __shared__ __align__(16) float buf[BUF_FLOATS];
    __shared__ __align__(16) float rbuf[64];

    const int lane = threadIdx.x;          // block == 1 wave
    const long chunk = blockIdx.x;
    if (chunk >= nchunks) return;

    // 9 DMA ops: x -> buf[0..1023], y -> buf[1024..2047], ref_e0123 -> rbuf.
    // Op k, lane L lands at base + L*16 B => float4 index k*64+L == global index.
    {
        const float4* gx = reinterpret_cast<const float4*>(x) + chunk * 256;
        const float4* gy = reinterpret_cast<const float4*>(y) + chunk * 256;
#pragma unroll
        for (int k = 0; k < 4; k++) {
            __builtin_amdgcn_global_load_lds((gas_ptr)(gx + k * 64 + lane),
                                             (las_ptr)(&buf[k * 256]), 16, 0, 0);
            __builtin_amdgcn_global_load_lds((gas_ptr)(gy + k * 64 + lane),
                                             (las_ptr)(&buf[1024 + k * 256]), 16, 0, 0);
        }
        __builtin_amdgcn_global_load_lds((gas_ptr)(ref + (chunk * 64 + lane) * 16 + 15),
                                         (las_ptr)(&rbuf[0]), 4, 0, 0);
    }

    asm volatile("s_waitcnt vmcnt(0)" ::: "memory");

    // ---- fragments: b128 LDS reads, point-major 64 B stride ----
    const float* bx = &buf[0];
    const float* by = &buf[1024];
    float xx[16], yy[16];
#pragma unroll
    for (int k = 0; k < 4; k++) {
        const float4 vx = *reinterpret_cast<const float4*>(bx + lane * 16 + k * 4);
        const float4 vy = *reinterpret_cast<const float4*>(by + lane * 16 + k * 4);
        xx[4*k+0] = vx.x; xx[4*k+1] = vx.y; xx[4*k+2] = vx.z; xx[4*k+3] = vx.w;
        yy[4*k+0] = vy.x; yy[4*k+1] = vy.y; yy[4*k+2] = vy.z; yy[4*k+3] = vy.w;
    }
    const float r = rbuf[lane];

    // ---- compute ----
    float gp[16] = {0.f, 0.f, 0.f, 0.f, 0.f, 0.f, 0.f, 0.f,
                    0.f, 0.f, 0.f, 0.f, 0.f, 0.f, 0.f, 0.f};
    float jn[16] = {0.f, 0.f, 0.f, 0.f, 0.f, 0.f, 0.f, 0.f,
                    0.f, 0.f, 0.f, 0.f, 0.f, 0.f, 0.f, 0.f};
#pragma unroll
    for (int t = 0; t < 192; t++) {
        const int ti = ga::G.t[t].i, tj = ga::G.t[t].j, tk = ga::G.t[t].k;
        const float v = xx[ti] * yy[tj];
        if (ga::G.t[t].s > 0) gp[tk] += v; else gp[tk] -= v;
    }
#pragma unroll
    for (int t = 0; t < 81; t++) {
        const int ti = ga::J.t[t].i, tj = ga::J.t[t].j, tk = ga::J.t[t].k;
        const float v = xx[ti] * yy[tj];
        if (ga::J.t[t].s > 0) jn[tk] += v; else jn[tk] -= v;
    }

    // Fence: frag reads stay above, lo-overlay writes stay below
    // (cross-lane WAR invisible to per-thread alias analysis — R3 lesson).
    asm volatile("" ::: "memory");

    // ---- stage results: 36-stride overlay over the buffer ----
    float* lo = &buf[0];
#pragma unroll
    for (int k = 0; k < 4; k++)
        *reinterpret_cast<float4*>(lo + lane * OSTRIDE + k * 4) =
            make_float4(gp[4*k+0], gp[4*k+1], gp[4*k+2], gp[4*k+3]);
#pragma unroll
    for (int k = 0; k < 4; k++)
        *reinterpret_cast<float4*>(lo + lane * OSTRIDE + 16 + k * 4) =
            make_float4(r * jn[4*k+0], r * jn[4*k+1], r * jn[4*k+2], r * jn[4*k+3]);

    // ---- cooperative unit-stride store: 512 float4 per chunk ----
    float4* go = reinterpret_cast<float4*>(out) + chunk * 512;
#pragma unroll
    for (int c = 0; c < 8; c++) {
        const int g  = lane + 64 * c;
        const int p  = g >> 3;
        const int ch = g & 7;
        go[g] = *reinterpret_cast<const float4*>(lo + p * OSTRIDE + ch * 4);
    }
}

// Tail path (npts not divisible by 64) — scalar per-thread, same math.
__global__ __launch_bounds__(64)
void MVGeometricBilinear_tail(const float* __restrict__ x,
                              const float* __restrict__ y,
                              const float* __restrict__ ref,
                              float* __restrict__ out,
                              int start, int npts)
{
    int pt = start + blockIdx.x * 64 + threadIdx.x;
    if (pt >= npts) return;
    float xx[16], yy[16];
#pragma unroll
    for (int k = 0; k < 16; k++) { xx[k] = x[(size_t)pt*16+k]; yy[k] = y[(size_t)pt*16+k]; }
    const float r = ref[(size_t)pt*16+15];
    float gp[16] = {}, jn[16] = {};
#pragma unroll
    for (int t = 0; t < 192; t++) {
        const float v = xx[ga::G.t[t].i] * yy[ga::G.t[t].j];
        if (ga::G.t[t].s > 0) gp[ga::G.t[t].k] += v; else gp[ga::G.t[t].k] -= v;
    }
#pragma unroll
    for (int t = 0; t < 81; t++) {
        const float v = xx[ga::J.t[t].i] * yy[ga::J.t[t].j];
        if (ga::J.t[t].s > 0) jn[ga::J.t[t].k] += v; else jn[ga::J.t[t].k] -= v;
    }
#pragma unroll
    for (int k = 0; k < 16; k++) out[(size_t)pt*32+k] = gp[k];
#pragma unroll
    for (int k = 0; k < 16; k++) out[(size_t)pt*32+16+k] = r * jn[k];
}

extern "C" void kernel_launch(void* const* d_in, const int* in_sizes, int n_in,
                              void* d_out, int out_size, void* d_ws, size_t ws_size,
                              hipStream_t stream) {
    const float* x   = (const float*)d_in[0];
    const float* y   = (const float*)d_in[1];
    const float* ref = (const float*)d_in[2];
    float* out = (float*)d_out;

    const int npts    = in_sizes[0] / 16;     // B*T = 524288
    const int nchunks = npts / 64;            // 8192

    if (nchunks > 0) {
        MVGeometricBilinear_kernel<<<nchunks, 64, 0, stream>>>(
            x, y, ref, out, nchunks);
    }

    const int rem = npts - nchunks * 64;      // 0 for this shape
    if (rem > 0) {
        MVGeometricBilinear_tail<<<(rem + 63) / 64, 64, 0, stream>>>(
            x, y, ref, out, nchunks * 64, npts);
    }
}